// Round 1
// baseline (315.917 us; speedup 1.0000x reference)
//
#include <hip/hip_runtime.h>
#include <hip/hip_bf16.h>
#include <math.h>

// Problem constants
#define B_BATCH 4
#define T_LEN   4096
#define D_DIM   1024
#define H_HEADS 16
#define NB_BINS 2049
#define M_ROWS  (B_BATCH * T_LEN)   // 16384

typedef __attribute__((ext_vector_type(8))) short short8;  // 8 bf16 (4 VGPRs)
typedef __attribute__((ext_vector_type(4))) float f32x4;   // MFMA accumulator

__device__ __forceinline__ ushort f2bf(float f) {
    unsigned b = __float_as_uint(f);
    unsigned r = (b + 0x7fffu + ((b >> 16) & 1u)) >> 16;   // RNE
    return (ushort)r;
}
__device__ __forceinline__ float bf2f(ushort u) {
    return __uint_as_float(((unsigned)u) << 16);
}

// ---------------------------------------------------------------- converts
__global__ void cvt_f32_to_bf16(const float* __restrict__ src, ushort* __restrict__ dst, int n4) {
    int i = blockIdx.x * 256 + threadIdx.x;
    if (i >= n4) return;
    float4 v = ((const float4*)src)[i];
    ushort4 o;
    o.x = f2bf(v.x); o.y = f2bf(v.y); o.z = f2bf(v.z); o.w = f2bf(v.w);
    ((ushort4*)dst)[i] = o;
}

// ---------------------------------------------------------------- twiddles
__global__ void prep_tw(float2* __restrict__ tw) {
    int k = blockIdx.x * 256 + threadIdx.x;
    if (k >= 4096) return;
    double th = -2.0 * 3.14159265358979323846 * (double)k / 4096.0;
    tw[k] = make_float2((float)cos(th), (float)sin(th));
}

__device__ __forceinline__ int rev4_12(int i) {
    int r = 0;
#pragma unroll
    for (int k = 0; k < 6; k++) { r = (r << 2) | (i & 3); i >>= 2; }
    return r;
}

// Digit-reversed full Hermitian filter table: Cdr[h][i] = Cfull[h][rev4(i)]
__global__ void prep_filter(const float* __restrict__ lg, const float* __restrict__ ph,
                            float2* __restrict__ Cdr) {
    int idx = blockIdx.x * 256 + threadIdx.x;      // h*4096 + i
    if (idx >= H_HEADS * 4096) return;
    int h = idx >> 12, i = idx & 4095;
    int f = rev4_12(i);
    int fc = (f <= 2048) ? f : (4096 - f);
    float sgn = (f <= 2048) ? 1.f : -1.f;
    float m = expf(lg[h * NB_BINS + fc]);
    float p = ph[h * NB_BINS + fc];
    float re = m * __cosf(p) , im = sgn * m * __sinf(p);
    if (fc == 0 || fc == 2048) im = 0.f;           // irfft c2r drops DC/Nyquist imag
    Cdr[idx] = make_float2(re, im);
}

// ---------------------------------------------------------------- GEMM (B^T input)
// C[m,n] = sum_k A[m,k]*B[n,k]  (+bias[n]) ; RESID: out f32 = resid + C ; else bf16 store
template<bool RESID>
__global__ void gemm_bt(const ushort* __restrict__ A, const ushort* __restrict__ Bm,
                        const float* __restrict__ bias, const float* __restrict__ resid,
                        void* __restrict__ Cout, int M, int N, int K) {
    __shared__ ushort As[128 * 32];
    __shared__ ushort Bs[128 * 32];
    const int tid  = threadIdx.x;
    const int lane = tid & 63;
    const int wid  = tid >> 6;
    const int wr   = wid >> 1, wc = wid & 1;
    const int nbn  = N >> 7;
    const int bm   = blockIdx.x / nbn, bn = blockIdx.x % nbn;
    const int row0 = bm << 7, col0 = bn << 7;

    f32x4 acc[4][4];
#pragma unroll
    for (int i = 0; i < 4; i++)
#pragma unroll
        for (int j = 0; j < 4; j++) acc[i][j] = (f32x4){0.f, 0.f, 0.f, 0.f};

    const int lrow = lane >> 2;         // 0..15 staging row
    const int lk   = (lane & 3) << 3;   // staging k offset (elements)
    const int fr   = lane & 15;         // fragment row/col
    const int kg   = (lane >> 4) << 3;  // fragment k group

    for (int k0 = 0; k0 < K; k0 += 32) {
#pragma unroll
        for (int i = 0; i < 2; i++) {
            int r = (wid << 5) + (i << 4);
            const ushort* ga = A  + (size_t)(row0 + r + lrow) * K + k0 + lk;
            const ushort* gb = Bm + (size_t)(col0 + r + lrow) * K + k0 + lk;
            __builtin_amdgcn_global_load_lds((const __attribute__((address_space(1))) void*)ga,
                (__attribute__((address_space(3))) void*)&As[r << 5], 16, 0, 0);
            __builtin_amdgcn_global_load_lds((const __attribute__((address_space(1))) void*)gb,
                (__attribute__((address_space(3))) void*)&Bs[r << 5], 16, 0, 0);
        }
        __syncthreads();   // drains vmcnt before barrier -> LDS tiles ready
        short8 af[4], bfr[4];
#pragma unroll
        for (int mi = 0; mi < 4; mi++)
            af[mi] = *(const short8*)&As[((wr << 6) + (mi << 4) + fr) * 32 + kg];
#pragma unroll
        for (int ni = 0; ni < 4; ni++)
            bfr[ni] = *(const short8*)&Bs[((wc << 6) + (ni << 4) + fr) * 32 + kg];
#pragma unroll
        for (int mi = 0; mi < 4; mi++)
#pragma unroll
            for (int ni = 0; ni < 4; ni++)
                acc[mi][ni] = __builtin_amdgcn_mfma_f32_16x16x32_bf16(af[mi], bfr[ni], acc[mi][ni], 0, 0, 0);
        __syncthreads();
    }

    const int crow = (lane >> 4) << 2;
#pragma unroll
    for (int mi = 0; mi < 4; mi++) {
#pragma unroll
        for (int ni = 0; ni < 4; ni++) {
            int row = row0 + (wr << 6) + (mi << 4) + crow;
            int col = col0 + (wc << 6) + (ni << 4) + fr;
            float bsv = bias[col];
#pragma unroll
            for (int j = 0; j < 4; j++) {
                float v = acc[mi][ni][j] + bsv;
                size_t off = (size_t)(row + j) * N + col;
                if (RESID) ((float*)Cout)[off] = resid[off] + v;
                else       ((ushort*)Cout)[off] = f2bf(v);
            }
        }
    }
}

// ---------------------------------------------------------------- FFT filter
// One block per (b, channel-pair). Pack v[d0] + i*v[d0+1], forward radix-4 DIF
// (natural->digit-reversed), multiply digit-reversed Hermitian filter, inverse
// radix-4 DIT (digit-reversed->natural), store re->d0, im->d0+1 (scaled 1/N).
__global__ __launch_bounds__(256) void fft_filter(const ushort* __restrict__ Vb,
                                                  ushort* __restrict__ yb,
                                                  const float2* __restrict__ tw,
                                                  const float2* __restrict__ Cdr) {
    __shared__ float2 X[4096];
    const int tid = threadIdx.x;
    const int b   = blockIdx.x >> 9;
    const int dp  = blockIdx.x & 511;
    const int d0  = dp << 1;
    const int h   = d0 >> 6;
    const uint* vsrc = (const uint*)Vb;

#pragma unroll
    for (int i = 0; i < 16; i++) {
        int t = tid + (i << 8);
        uint u = vsrc[(((size_t)b * 4096 + t) * 1024 + d0) >> 1];
        X[t] = make_float2(bf2f((ushort)(u & 0xffffu)), bf2f((ushort)(u >> 16)));
    }
    __syncthreads();

    // forward DIF
    for (int ln = 12; ln >= 2; ln -= 2) {
        const int mshift = ln - 2;
        const int m = 1 << mshift;
        const int ts = 12 - ln;
#pragma unroll
        for (int i = 0; i < 4; i++) {
            int idx = tid + (i << 8);
            int p = idx & (m - 1);
            int base = ((idx >> mshift) << ln) + p;
            float2 a = X[base], bb = X[base + m], c = X[base + 2 * m], d = X[base + 3 * m];
            float apcx = a.x + c.x, apcy = a.y + c.y;
            float amcx = a.x - c.x, amcy = a.y - c.y;
            float bpdx = bb.x + d.x, bpdy = bb.y + d.y;
            float jbx = -(bb.y - d.y), jby = (bb.x - d.x);   // j*(b-d)
            X[base] = make_float2(apcx + bpdx, apcy + bpdy);
            int t1 = p << ts;
            float2 w1 = tw[t1], w2 = tw[t1 << 1], w3 = tw[t1 * 3];
            float s1x = amcx - jbx, s1y = amcy - jby;
            float s2x = apcx - bpdx, s2y = apcy - bpdy;
            float s3x = amcx + jbx, s3y = amcy + jby;
            X[base + m]     = make_float2(w1.x * s1x - w1.y * s1y, w1.x * s1y + w1.y * s1x);
            X[base + 2 * m] = make_float2(w2.x * s2x - w2.y * s2y, w2.x * s2y + w2.y * s2x);
            X[base + 3 * m] = make_float2(w3.x * s3x - w3.y * s3y, w3.x * s3y + w3.y * s3x);
        }
        __syncthreads();
    }

    // pointwise filter (digit-reversed order)
    const float2* Ch = Cdr + (h << 12);
#pragma unroll
    for (int i = 0; i < 16; i++) {
        int t = tid + (i << 8);
        float2 v = X[t], cc = Ch[t];
        X[t] = make_float2(v.x * cc.x - v.y * cc.y, v.x * cc.y + v.y * cc.x);
    }
    __syncthreads();

    // inverse DIT (conjugate twiddles), 1/N folded into the store
    for (int ln = 2; ln <= 12; ln += 2) {
        const int mshift = ln - 2;
        const int m = 1 << mshift;
        const int ts = 12 - ln;
#pragma unroll
        for (int i = 0; i < 4; i++) {
            int idx = tid + (i << 8);
            int p = idx & (m - 1);
            int base = ((idx >> mshift) << ln) + p;
            float2 t0 = X[base];
            float2 u1 = X[base + m], u2 = X[base + 2 * m], u3 = X[base + 3 * m];
            int t1i = p << ts;
            float2 w1 = tw[t1i], w2 = tw[t1i << 1], w3 = tw[t1i * 3];
            float t1x = w1.x * u1.x + w1.y * u1.y, t1y = w1.x * u1.y - w1.y * u1.x;
            float t2x = w2.x * u2.x + w2.y * u2.y, t2y = w2.x * u2.y - w2.y * u2.x;
            float t3x = w3.x * u3.x + w3.y * u3.y, t3y = w3.x * u3.y - w3.y * u3.x;
            float s02px = t0.x + t2x, s02py = t0.y + t2y;
            float s02mx = t0.x - t2x, s02my = t0.y - t2y;
            float s13px = t1x + t3x, s13py = t1y + t3y;
            float jsx = -(t1y - t3y), jsy = (t1x - t3x);     // j*(t1-t3)
            X[base]         = make_float2(s02px + s13px, s02py + s13py);
            X[base + m]     = make_float2(s02mx + jsx, s02my + jsy);
            X[base + 2 * m] = make_float2(s02px - s13px, s02py - s13py);
            X[base + 3 * m] = make_float2(s02mx - jsx, s02my - jsy);
        }
        __syncthreads();
    }

    uint* ydst = (uint*)yb;
    const float sc = 1.0f / 4096.0f;
#pragma unroll
    for (int i = 0; i < 16; i++) {
        int t = tid + (i << 8);
        float2 v = X[t];
        uint pk = (uint)f2bf(v.x * sc) | ((uint)f2bf(v.y * sc) << 16);
        ydst[(((size_t)b * 4096 + t) * 1024 + d0) >> 1] = pk;
    }
}

// ---------------------------------------------------------------- launch
extern "C" void kernel_launch(void* const* d_in, const int* in_sizes, int n_in,
                              void* d_out, int out_size, void* d_ws, size_t ws_size,
                              hipStream_t stream) {
    const float* x    = (const float*)d_in[0];
    const float* Wqkv = (const float*)d_in[1];
    const float* bqkv = (const float*)d_in[2];
    const float* Wo   = (const float*)d_in[3];
    const float* bo   = (const float*)d_in[4];
    const float* lg   = (const float*)d_in[5];
    const float* ph   = (const float*)d_in[6];

    char* ws = (char*)d_ws;
    ushort* xb  = (ushort*)ws;                      // 33,554,432 B (x bf16; reused as y bf16)
    ushort* Wvb = (ushort*)(ws + 33554432);         //  2,097,152 B
    ushort* Wob = (ushort*)(ws + 35651584);         //  2,097,152 B
    float2* tw  = (float2*)(ws + 37748736);         //     32,768 B
    float2* Cdr = (float2*)(ws + 37781504);         //    524,288 B
    ushort* Vb  = (ushort*)d_out;                   // V bf16 scratch inside output buffer
    ushort* yb  = xb;
    float*  out = (float*)d_out;

    prep_tw<<<16, 256, 0, stream>>>(tw);
    prep_filter<<<(H_HEADS * 4096) / 256, 256, 0, stream>>>(lg, ph, Cdr);
    cvt_f32_to_bf16<<<(16777216 / 4) / 256, 256, 0, stream>>>(x, xb, 16777216 / 4);
    cvt_f32_to_bf16<<<(1048576 / 4) / 256, 256, 0, stream>>>(Wqkv + 2048 * 1024, Wvb, 1048576 / 4);
    cvt_f32_to_bf16<<<(1048576 / 4) / 256, 256, 0, stream>>>(Wo, Wob, 1048576 / 4);

    // V = x @ Wv^T (+b_qkv[2D:]) -> bf16 into d_out scratch
    gemm_bt<false><<<(M_ROWS / 128) * (D_DIM / 128), 256, 0, stream>>>(
        xb, Wvb, bqkv + 2 * D_DIM, nullptr, (void*)Vb, M_ROWS, D_DIM, D_DIM);

    // spectral filter along T (overwrites xb with y bf16)
    fft_filter<<<B_BATCH * (D_DIM / 2), 256, 0, stream>>>(Vb, yb, tw, Cdr);

    // out = x + y @ Wo^T (+b_o)
    gemm_bt<true><<<(M_ROWS / 128) * (D_DIM / 128), 256, 0, stream>>>(
        yb, Wob, bo, x, (void*)out, M_ROWS, D_DIM, D_DIM);
}

// Round 2
// 197.977 us; speedup vs baseline: 1.5957x; 1.5957x over previous
//
#include <hip/hip_runtime.h>
#include <hip/hip_bf16.h>
#include <math.h>

#define B_BATCH 4
#define T_LEN   4096
#define D_DIM   1024
#define H_HEADS 16
#define NB_BINS 2049
#define M_ROWS  (B_BATCH * T_LEN)   // 16384

typedef __attribute__((ext_vector_type(8))) short short8;           // 8 bf16
typedef __attribute__((ext_vector_type(8))) unsigned short u16x8;   // 8 u16
typedef __attribute__((ext_vector_type(4))) float f32x4;

__device__ __forceinline__ ushort f2bf(float f) {
    unsigned b = __float_as_uint(f);
    unsigned r = (b + 0x7fffu + ((b >> 16) & 1u)) >> 16;   // RNE
    return (ushort)r;
}
__device__ __forceinline__ float bf2f(ushort u) {
    return __uint_as_float(((unsigned)u) << 16);
}

// ---------------------------------------------------------------- converts
__global__ void cvt_f32_to_bf16(const float* __restrict__ src, ushort* __restrict__ dst, int n4) {
    int i = blockIdx.x * 256 + threadIdx.x;
    if (i >= n4) return;
    float4 v = ((const float4*)src)[i];
    ushort4 o;
    o.x = f2bf(v.x); o.y = f2bf(v.y); o.z = f2bf(v.z); o.w = f2bf(v.w);
    ((ushort4*)dst)[i] = o;
}

// ---------------------------------------------------------------- tables
__global__ void prep_tw(float2* __restrict__ tw) {
    int k = blockIdx.x * 256 + threadIdx.x;
    if (k >= 4096) return;
    double th = -2.0 * 3.14159265358979323846 * (double)k / 4096.0;
    tw[k] = make_float2((float)cos(th), (float)sin(th));
}

// base-16 3-digit reversal of i in [0,4096)
__device__ __forceinline__ int drev16(int i) {
    return ((i & 15) << 8) | (i & 0xF0) | (i >> 8);
}

// Filter table in radix-16 digit-reversed order: Cdr[h][i] = Cfull[h][drev16(i)]
__global__ void prep_filter16(const float* __restrict__ lg, const float* __restrict__ ph,
                              float2* __restrict__ Cdr) {
    int idx = blockIdx.x * 256 + threadIdx.x;
    if (idx >= H_HEADS * 4096) return;
    int h = idx >> 12, i = idx & 4095;
    int f = drev16(i);
    int fc = (f <= 2048) ? f : (4096 - f);
    float sgn = (f <= 2048) ? 1.f : -1.f;
    float m = expf(lg[h * NB_BINS + fc]);
    float p = ph[h * NB_BINS + fc];
    float re = m * __cosf(p), im = sgn * m * __sinf(p);
    if (fc == 0 || fc == 2048) im = 0.f;       // irfft c2r drops DC/Nyquist imag
    Cdr[idx] = make_float2(re, im);
}

// ---------------------------------------------------------------- GEMM (B^T input)
// C[m,n] = sum_k A[m,k]*B[n,k]; BIASROW: bias[row] else bias[col];
// RESID: f32 out = resid + C, else bf16 store.
template<bool RESID, bool BIASROW>
__global__ void gemm_bt(const ushort* __restrict__ A, const ushort* __restrict__ Bm,
                        const float* __restrict__ bias, const float* __restrict__ resid,
                        void* __restrict__ Cout, int M, int N, int K) {
    __shared__ ushort As[128 * 32];
    __shared__ ushort Bs[128 * 32];
    const int tid  = threadIdx.x;
    const int lane = tid & 63;
    const int wid  = tid >> 6;
    const int wr   = wid >> 1, wc = wid & 1;
    const int nbn  = N >> 7;
    const int bm   = blockIdx.x / nbn, bn = blockIdx.x % nbn;
    const int row0 = bm << 7, col0 = bn << 7;

    f32x4 acc[4][4];
#pragma unroll
    for (int i = 0; i < 4; i++)
#pragma unroll
        for (int j = 0; j < 4; j++) acc[i][j] = (f32x4){0.f, 0.f, 0.f, 0.f};

    const int lrow = lane >> 2;
    const int lk   = (lane & 3) << 3;
    const int fr   = lane & 15;
    const int kg   = (lane >> 4) << 3;

    for (int k0 = 0; k0 < K; k0 += 32) {
#pragma unroll
        for (int i = 0; i < 2; i++) {
            int r = (wid << 5) + (i << 4);
            const ushort* ga = A  + (size_t)(row0 + r + lrow) * K + k0 + lk;
            const ushort* gb = Bm + (size_t)(col0 + r + lrow) * K + k0 + lk;
            __builtin_amdgcn_global_load_lds((const __attribute__((address_space(1))) void*)ga,
                (__attribute__((address_space(3))) void*)&As[r << 5], 16, 0, 0);
            __builtin_amdgcn_global_load_lds((const __attribute__((address_space(1))) void*)gb,
                (__attribute__((address_space(3))) void*)&Bs[r << 5], 16, 0, 0);
        }
        __syncthreads();
        short8 af[4], bfr[4];
#pragma unroll
        for (int mi = 0; mi < 4; mi++)
            af[mi] = *(const short8*)&As[((wr << 6) + (mi << 4) + fr) * 32 + kg];
#pragma unroll
        for (int ni = 0; ni < 4; ni++)
            bfr[ni] = *(const short8*)&Bs[((wc << 6) + (ni << 4) + fr) * 32 + kg];
#pragma unroll
        for (int mi = 0; mi < 4; mi++)
#pragma unroll
            for (int ni = 0; ni < 4; ni++)
                acc[mi][ni] = __builtin_amdgcn_mfma_f32_16x16x32_bf16(af[mi], bfr[ni], acc[mi][ni], 0, 0, 0);
        __syncthreads();
    }

    const int crow = (lane >> 4) << 2;
#pragma unroll
    for (int mi = 0; mi < 4; mi++) {
#pragma unroll
        for (int ni = 0; ni < 4; ni++) {
            int row = row0 + (wr << 6) + (mi << 4) + crow;
            int col = col0 + (wc << 6) + (ni << 4) + fr;
            float bcol = BIASROW ? 0.f : bias[col];
#pragma unroll
            for (int j = 0; j < 4; j++) {
                float v = acc[mi][ni][j] + (BIASROW ? bias[row + j] : bcol);
                size_t off = (size_t)(row + j) * N + col;
                if (RESID) ((float*)Cout)[off] = resid[off] + v;
                else       ((ushort*)Cout)[off] = f2bf(v);
            }
        }
    }
}

// ---------------------------------------------------------------- FFT radix-16
__device__ __forceinline__ float2 cadd(float2 a, float2 b){ return make_float2(a.x+b.x, a.y+b.y); }
__device__ __forceinline__ float2 csub(float2 a, float2 b){ return make_float2(a.x-b.x, a.y-b.y); }
__device__ __forceinline__ float2 jmulp(float2 z){ return make_float2(-z.y, z.x); }        // +j*z
__device__ __forceinline__ float2 cmul(float2 a, float2 b){
    return make_float2(fmaf(a.x,b.x,-a.y*b.y), fmaf(a.x,b.y, a.y*b.x)); }
__device__ __forceinline__ float2 cmulc(float2 a, float2 b){   // a * conj(b)
    return make_float2(fmaf(a.x,b.x, a.y*b.y), fmaf(a.y,b.x,-a.x*b.y)); }

template<int INV>
__device__ __forceinline__ void bf4(float2& a, float2& b, float2& c, float2& d) {
    float2 acp = cadd(a,c), acm = csub(a,c);
    float2 bdp = cadd(b,d), bdm = csub(b,d);
    float2 jb  = jmulp(bdm);
    a = cadd(acp, bdp);
    c = csub(acp, bdp);
    if (INV) { b = cadd(acm, jb); d = csub(acm, jb); }
    else     { b = csub(acm, jb); d = cadd(acm, jb); }
}

#define C16_1 0.9238795325112867f
#define S16_1 0.3826834323650898f
#define R16_2 0.7071067811865476f

// DFT-16: input v[j] natural order; output X[k0+4k1] lands in v[4k0+k1].
template<int INV>
__device__ __forceinline__ void dft16(float2 v[16]) {
    const float sg = INV ? 1.f : -1.f;
    bf4<INV>(v[0], v[4], v[8],  v[12]);
    bf4<INV>(v[1], v[5], v[9],  v[13]);
    bf4<INV>(v[2], v[6], v[10], v[14]);
    bf4<INV>(v[3], v[7], v[11], v[15]);
    const float2 w1 = make_float2( C16_1, sg*S16_1);
    const float2 w2 = make_float2( R16_2, sg*R16_2);
    const float2 w3 = make_float2( S16_1, sg*C16_1);
    const float2 w6 = make_float2(-R16_2, sg*R16_2);
    const float2 w9 = make_float2(-C16_1,-sg*S16_1);
    v[5]  = cmul(v[5],  w1);
    v[6]  = cmul(v[6],  w2);
    v[7]  = cmul(v[7],  w3);
    v[9]  = cmul(v[9],  w2);
    v[10] = INV ? jmulp(v[10]) : make_float2(v[10].y, -v[10].x);
    v[11] = cmul(v[11], w6);
    v[13] = cmul(v[13], w3);
    v[14] = cmul(v[14], w6);
    v[15] = cmul(v[15], w9);
    bf4<INV>(v[0],  v[1],  v[2],  v[3]);
    bf4<INV>(v[4],  v[5],  v[6],  v[7]);
    bf4<INV>(v[8],  v[9],  v[10], v[11]);
    bf4<INV>(v[12], v[13], v[14], v[15]);
}

__host__ __device__ constexpr int oidx(int r) { return ((r & 3) << 2) | (r >> 2); }

// LDS bank swizzle (involution): spreads strides 1/16/256 across bank pairs
__device__ __forceinline__ int phz(int t) { return t ^ (((t >> 4) ^ (t >> 8)) & 15); }

// One block per (b, channel-pair). V^T rows d0,d0+1 -> complex pack -> 3x radix-16
// fwd (natural -> digit-reversed) -> filter -> 3x radix-16 inv -> y^T rows.
__global__ __launch_bounds__(256) void fft16_filter(const ushort* __restrict__ VT,
                                                    ushort* __restrict__ yT,
                                                    const float2* __restrict__ tw,
                                                    const float2* __restrict__ Cdr) {
    __shared__ float2 X[4096];
    const int tid = threadIdx.x;
    const int b   = blockIdx.x >> 9;
    const int dp  = blockIdx.x & 511;
    const int d0  = dp << 1;
    const int h   = dp >> 5;

    const ushort* srcRe = VT + (size_t)d0 * M_ROWS + b * T_LEN;
    const ushort* srcIm = VT + (size_t)(d0 + 1) * M_ROWS + b * T_LEN;

    float2 v[16];
#pragma unroll
    for (int j = 0; j < 16; j++)
        v[j] = make_float2(bf2f(srcRe[tid + (j << 8)]), bf2f(srcIm[tid + (j << 8)]));

    // ---- forward stage 1 (m=256), twiddle W^{p*r}, p=tid
    dft16<0>(v);
#pragma unroll
    for (int r = 1; r < 16; r++) v[oidx(r)] = cmul(v[oidx(r)], tw[tid * r]);
#pragma unroll
    for (int r = 0; r < 16; r++) X[phz(tid + (r << 8))] = v[oidx(r)];
    __syncthreads();

    // ---- forward stage 2 (m=16), twiddle W^{16*p*r}
    const int p2 = tid & 15, g2 = tid >> 4;
    const int base2 = (g2 << 8) + p2;
#pragma unroll
    for (int j = 0; j < 16; j++) v[j] = X[phz(base2 + (j << 4))];
    dft16<0>(v);
#pragma unroll
    for (int r = 1; r < 16; r++) v[oidx(r)] = cmul(v[oidx(r)], tw[(p2 * r) << 4]);
    __syncthreads();
#pragma unroll
    for (int r = 0; r < 16; r++) X[phz(base2 + (r << 4))] = v[oidx(r)];
    __syncthreads();

    // ---- forward stage 3 (m=1, no twiddle) + filter + inverse stage 1: in regs
    const int base3 = tid << 4;
#pragma unroll
    for (int j = 0; j < 16; j++) v[j] = X[phz(base3 + j)];
    dft16<0>(v);
    const float2* Ch = Cdr + (h << 12) + base3;
#pragma unroll
    for (int r = 0; r < 16; r++) v[oidx(r)] = cmul(v[oidx(r)], Ch[r]);
    float2 u[16];
#pragma unroll
    for (int j = 0; j < 16; j++) u[j] = v[oidx(j)];
    dft16<1>(u);
    __syncthreads();
#pragma unroll
    for (int r = 0; r < 16; r++) X[phz(base3 + r)] = u[oidx(r)];
    __syncthreads();

    // ---- inverse stage 2 (m=16): un-twiddle then IDFT
#pragma unroll
    for (int j = 0; j < 16; j++) v[j] = X[phz(base2 + (j << 4))];
#pragma unroll
    for (int j = 1; j < 16; j++) v[j] = cmulc(v[j], tw[(p2 * j) << 4]);
    dft16<1>(v);
    __syncthreads();
#pragma unroll
    for (int r = 0; r < 16; r++) X[phz(base2 + (r << 4))] = v[oidx(r)];
    __syncthreads();

    // ---- inverse stage 3 (m=256) + coalesced store (scaled 1/N)
#pragma unroll
    for (int j = 0; j < 16; j++) v[j] = X[phz(tid + (j << 8))];
#pragma unroll
    for (int j = 1; j < 16; j++) v[j] = cmulc(v[j], tw[tid * j]);
    dft16<1>(v);
    ushort* dstRe = yT + (size_t)d0 * M_ROWS + b * T_LEN;
    ushort* dstIm = yT + (size_t)(d0 + 1) * M_ROWS + b * T_LEN;
    const float sc = 1.0f / 4096.0f;
#pragma unroll
    for (int r = 0; r < 16; r++) {
        float2 val = v[oidx(r)];
        dstRe[tid + (r << 8)] = f2bf(val.x * sc);
        dstIm[tid + (r << 8)] = f2bf(val.y * sc);
    }
}

// ---------------------------------------------------------------- transpose
// y^T [1024][16384] -> y [16384][1024], 64x64 tiles, XOR-swizzled LDS
__global__ __launch_bounds__(256) void transpose_yT(const ushort* __restrict__ src,
                                                    ushort* __restrict__ dst) {
    __shared__ ushort tile[4096];
    const int tid = threadIdx.x;
    const int bm = blockIdx.x & 255;
    const int bd = blockIdx.x >> 8;
    const int m0 = bm << 6, d0 = bd << 6;
#pragma unroll
    for (int i = 0; i < 2; i++) {
        int vn = tid + (i << 8);
        int r  = vn >> 3;              // d row 0..63
        int c8 = (vn & 7) << 3;        // m col base
        u16x8 val = *(const u16x8*)&src[(size_t)(d0 + r) * M_ROWS + m0 + c8];
#pragma unroll
        for (int q = 0; q < 8; q++)
            tile[(r << 6) | ((c8 + q) ^ r)] = (ushort)val[q];
    }
    __syncthreads();
    const int dc = tid & 63;
    const int wb = tid >> 6;
#pragma unroll
    for (int i = 0; i < 16; i++) {
        int mr = wb + (i << 2);
        dst[(size_t)(m0 + mr) * D_DIM + d0 + dc] = tile[(dc << 6) | (mr ^ dc)];
    }
}

// ---------------------------------------------------------------- launch
extern "C" void kernel_launch(void* const* d_in, const int* in_sizes, int n_in,
                              void* d_out, int out_size, void* d_ws, size_t ws_size,
                              hipStream_t stream) {
    const float* x    = (const float*)d_in[0];
    const float* Wqkv = (const float*)d_in[1];
    const float* bqkv = (const float*)d_in[2];
    const float* Wo   = (const float*)d_in[3];
    const float* bo   = (const float*)d_in[4];
    const float* lg   = (const float*)d_in[5];
    const float* ph   = (const float*)d_in[6];

    char* ws = (char*)d_ws;
    ushort* xb  = (ushort*)ws;                      // 33,554,432 B: x bf16; later y natural
    ushort* Wvb = (ushort*)(ws + 33554432);         //  2,097,152 B
    ushort* Wob = (ushort*)(ws + 35651584);         //  2,097,152 B
    float2* tw  = (float2*)(ws + 37748736);         //     32,768 B
    float2* Cdr = (float2*)(ws + 37781504);         //    524,288 B

    ushort* VT   = (ushort*)d_out;                          // [1024][16384] lower half
    ushort* yT   = (ushort*)((char*)d_out + 33554432);      // [1024][16384] upper half
    ushort* ynat = xb;                                      // [16384][1024] after gemm1
    float*  out  = (float*)d_out;

    prep_tw<<<16, 256, 0, stream>>>(tw);
    prep_filter16<<<(H_HEADS * 4096) / 256, 256, 0, stream>>>(lg, ph, Cdr);
    cvt_f32_to_bf16<<<(16777216 / 4) / 256, 256, 0, stream>>>(x, xb, 16777216 / 4);
    cvt_f32_to_bf16<<<(1048576 / 4) / 256, 256, 0, stream>>>(Wqkv + 2048 * 1024, Wvb, 1048576 / 4);
    cvt_f32_to_bf16<<<(1048576 / 4) / 256, 256, 0, stream>>>(Wo, Wob, 1048576 / 4);

    // V^T[d][m] = sum_k Wv[d,k] x[m,k] + b_qkv[2D+d]  (operand-swapped GEMM)
    gemm_bt<false, true><<<(D_DIM / 128) * (M_ROWS / 128), 256, 0, stream>>>(
        Wvb, xb, bqkv + 2 * D_DIM, nullptr, (void*)VT, D_DIM, M_ROWS, D_DIM);

    // spectral filter along T, coalesced rows: V^T -> y^T
    fft16_filter<<<B_BATCH * (D_DIM / 2), 256, 0, stream>>>(VT, yT, tw, Cdr);

    // y^T -> y natural layout (into xb, free after gemm1)
    transpose_yT<<<(M_ROWS / 64) * (D_DIM / 64), 256, 0, stream>>>(yT, ynat);

    // out = x + y @ Wo^T + b_o
    gemm_bt<true, false><<<(M_ROWS / 128) * (D_DIM / 128), 256, 0, stream>>>(
        ynat, Wob, bo, x, (void*)out, M_ROWS, D_DIM, D_DIM);
}

// Round 3
// 188.803 us; speedup vs baseline: 1.6733x; 1.0486x over previous
//
#include <hip/hip_runtime.h>
#include <hip/hip_bf16.h>
#include <math.h>

#define B_BATCH 4
#define T_LEN   4096
#define D_DIM   1024
#define H_HEADS 16
#define NB_BINS 2049
#define M_ROWS  (B_BATCH * T_LEN)   // 16384

typedef __attribute__((ext_vector_type(8))) short short8;           // 8 bf16
typedef __attribute__((ext_vector_type(8))) unsigned short u16x8;   // 8 u16
typedef __attribute__((ext_vector_type(4))) float f32x4;

__device__ __forceinline__ ushort f2bf(float f) {
    unsigned b = __float_as_uint(f);
    unsigned r = (b + 0x7fffu + ((b >> 16) & 1u)) >> 16;   // RNE
    return (ushort)r;
}
__device__ __forceinline__ float bf2f(ushort u) {
    return __uint_as_float(((unsigned)u) << 16);
}

// ---------------------------------------------------------------- converts
__global__ void cvt_f32_to_bf16(const float* __restrict__ src, ushort* __restrict__ dst, int n4) {
    int i = blockIdx.x * 256 + threadIdx.x;
    if (i >= n4) return;
    float4 v = ((const float4*)src)[i];
    ushort4 o;
    o.x = f2bf(v.x); o.y = f2bf(v.y); o.z = f2bf(v.z); o.w = f2bf(v.w);
    ((ushort4*)dst)[i] = o;
}

// ---------------------------------------------------------------- tables
__global__ void prep_tw(float2* __restrict__ tw) {
    int k = blockIdx.x * 256 + threadIdx.x;
    if (k >= 4096) return;
    double th = -2.0 * 3.14159265358979323846 * (double)k / 4096.0;
    tw[k] = make_float2((float)cos(th), (float)sin(th));
}

__device__ __forceinline__ int drev16(int i) {
    return ((i & 15) << 8) | (i & 0xF0) | (i >> 8);
}

__global__ void prep_filter16(const float* __restrict__ lg, const float* __restrict__ ph,
                              float2* __restrict__ Cdr) {
    int idx = blockIdx.x * 256 + threadIdx.x;
    if (idx >= H_HEADS * 4096) return;
    int h = idx >> 12, i = idx & 4095;
    int f = drev16(i);
    int fc = (f <= 2048) ? f : (4096 - f);
    float sgn = (f <= 2048) ? 1.f : -1.f;
    float m = expf(lg[h * NB_BINS + fc]);
    float p = ph[h * NB_BINS + fc];
    float re = m * __cosf(p), im = sgn * m * __sinf(p);
    if (fc == 0 || fc == 2048) im = 0.f;       // irfft c2r drops DC/Nyquist imag
    Cdr[idx] = make_float2(re, im);
}

// ---------------------------------------------------------------- GEMM 256x256, BK=32, 3-deep pipeline
// C[m,n] = sum_k A[m,k]*B[n,k]; BIASROW: bias[row] else bias[col];
// RESID: f32 out = resid + C, else bf16 store. M,N multiples of 256, K of 32.
template<bool RESID, bool BIASROW>
__global__ __launch_bounds__(512, 2) void gemm256(const ushort* __restrict__ A,
        const ushort* __restrict__ Bm, const float* __restrict__ bias,
        const float* __restrict__ resid, void* __restrict__ Cout,
        int M, int N, int K) {
    // LDS: A bufs at 0/8192/16384 ushorts, B bufs at 24576/32768/40960 (96 KiB)
    __shared__ ushort lds[49152];
    const int tid  = threadIdx.x;
    const int lane = tid & 63;
    const int wid  = tid >> 6;           // 0..7
    const int wr   = wid >> 2, wc = wid & 3;   // 2 x 4 wave grid
    const int fr   = lane & 15;
    const int nbn  = N >> 8;
    int bid = (int)blockIdx.x;
    bid = (bid & 7) * ((int)gridDim.x >> 3) + (bid >> 3);   // XCD swizzle (grid % 8 == 0)
    const int bm = bid / nbn, bn = bid % nbn;
    const int row0 = bm << 8, col0 = bn << 8;
    const int NT = K >> 5;

    f32x4 acc[8][4];
#pragma unroll
    for (int i = 0; i < 8; i++)
#pragma unroll
        for (int j = 0; j < 4; j++) acc[i][j] = (f32x4){0.f, 0.f, 0.f, 0.f};

    // stage one 256x32 bf16 panel into LDS base lb (ushort idx). Linear LDS dest
    // (global_load_lds writes base+lane*16); bank swizzle achieved by XORing the
    // SOURCE column group with (row&3) — inverse of the ds_read swizzle below.
    auto stage = [&](const ushort* P, int gr0, int k0, int lb) {
#pragma unroll
        for (int i = 0; i < 2; i++) {
            int r = (wid << 5) + (i << 4) + (lane >> 2);
            int c = ((lane & 3) ^ ((lane >> 2) & 3)) << 3;
            const ushort* g = P + (size_t)(gr0 + r) * (size_t)K + (size_t)(k0 + c);
            __builtin_amdgcn_global_load_lds(
                (const __attribute__((address_space(1))) void*)g,
                (__attribute__((address_space(3))) void*)&lds[lb + (((wid << 1) + i) << 9)],
                16, 0, 0);
        }
    };
    // read one 16x32 MFMA fragment: lane holds row (base+fr), k = (lane>>4)*8..+8
    auto rdfrag = [&](int base, int row) -> short8 {
        int g = (((lane >> 4) ^ (row & 3)) << 3);
        return *(const short8*)&lds[base + (row << 5) + g];
    };

    // prologue: stage tiles 0 and 1; drain tile 0, leave tile 1 in flight
    stage(A,  row0, 0, 0);
    stage(Bm, col0, 0, 24576);
    stage(A,  row0, 32, 8192);
    stage(Bm, col0, 32, 24576 + 8192);
    asm volatile("s_waitcnt vmcnt(4)" ::: "memory");
    __builtin_amdgcn_sched_barrier(0);
    __builtin_amdgcn_s_barrier();

    short8 aF[4], bF[4];
    for (int t = 0; t < NT; ++t) {
        const int cb = (t % 3) << 13;           // current buf (ushort offset)
        const int sb = ((t + 2) % 3) << 13;     // stage buf for tile t+2
        const bool st = (t + 2) < NT;
        const int k2 = (t + 2) << 5;

        // ---------- phase 0 (M-half 0): reads + stage A(t+2)
#pragma unroll
        for (int mi = 0; mi < 4; mi++) aF[mi] = rdfrag(cb, (wr << 7) + (mi << 4) + fr);
#pragma unroll
        for (int ni = 0; ni < 4; ni++) bF[ni] = rdfrag(24576 + cb, (wc << 6) + (ni << 4) + fr);
        if (st) stage(A, row0, k2, sb);
        __builtin_amdgcn_s_barrier();
        asm volatile("s_waitcnt lgkmcnt(0)" ::: "memory");
        __builtin_amdgcn_sched_barrier(0);
        __builtin_amdgcn_s_setprio(1);
#pragma unroll
        for (int mi = 0; mi < 4; mi++)
#pragma unroll
            for (int ni = 0; ni < 4; ni++)
                acc[mi][ni] = __builtin_amdgcn_mfma_f32_16x16x32_bf16(aF[mi], bF[ni], acc[mi][ni], 0, 0, 0);
        __builtin_amdgcn_s_setprio(0);
        __builtin_amdgcn_sched_barrier(0);
        __builtin_amdgcn_s_barrier();

        // ---------- phase 1 (M-half 1): reads + stage B(t+2)
#pragma unroll
        for (int mi = 0; mi < 4; mi++) aF[mi] = rdfrag(cb, (wr << 7) + 64 + (mi << 4) + fr);
        if (st) stage(Bm, col0, k2, 24576 + sb);
        __builtin_amdgcn_s_barrier();
        asm volatile("s_waitcnt lgkmcnt(0)" ::: "memory");
        __builtin_amdgcn_sched_barrier(0);
        __builtin_amdgcn_s_setprio(1);
#pragma unroll
        for (int mi = 0; mi < 4; mi++)
#pragma unroll
            for (int ni = 0; ni < 4; ni++)
                acc[4 + mi][ni] = __builtin_amdgcn_mfma_f32_16x16x32_bf16(aF[mi], bF[ni], acc[4 + mi][ni], 0, 0, 0);
        __builtin_amdgcn_s_setprio(0);
        __builtin_amdgcn_sched_barrier(0);
        // tile boundary: drain tile t+1's 4 staging loads (leave t+2's flying),
        // BEFORE the barrier so all waves' ds_reads next tile see staged data.
        if (t + 1 < NT) {
            if (st) asm volatile("s_waitcnt vmcnt(4)" ::: "memory");
            else    asm volatile("s_waitcnt vmcnt(0)" ::: "memory");
        }
        __builtin_amdgcn_s_barrier();
    }

    // epilogue
    const int crow = (lane >> 4) << 2;
#pragma unroll
    for (int mi = 0; mi < 8; mi++) {
#pragma unroll
        for (int ni = 0; ni < 4; ni++) {
            int row = row0 + (wr << 7) + (mi << 4) + crow;
            int col = col0 + (wc << 6) + (ni << 4) + fr;
            float bcol = BIASROW ? 0.f : bias[col];
#pragma unroll
            for (int j = 0; j < 4; j++) {
                float v = acc[mi][ni][j] + (BIASROW ? bias[row + j] : bcol);
                size_t off = (size_t)(row + j) * N + col;
                if (RESID) ((float*)Cout)[off] = resid[off] + v;
                else       ((ushort*)Cout)[off] = f2bf(v);
            }
        }
    }
}

// ---------------------------------------------------------------- FFT radix-16
__device__ __forceinline__ float2 cadd(float2 a, float2 b){ return make_float2(a.x+b.x, a.y+b.y); }
__device__ __forceinline__ float2 csub(float2 a, float2 b){ return make_float2(a.x-b.x, a.y-b.y); }
__device__ __forceinline__ float2 jmulp(float2 z){ return make_float2(-z.y, z.x); }        // +j*z
__device__ __forceinline__ float2 cmul(float2 a, float2 b){
    return make_float2(fmaf(a.x,b.x,-a.y*b.y), fmaf(a.x,b.y, a.y*b.x)); }
__device__ __forceinline__ float2 cmulc(float2 a, float2 b){   // a * conj(b)
    return make_float2(fmaf(a.x,b.x, a.y*b.y), fmaf(a.y,b.x,-a.x*b.y)); }

template<int INV>
__device__ __forceinline__ void bf4(float2& a, float2& b, float2& c, float2& d) {
    float2 acp = cadd(a,c), acm = csub(a,c);
    float2 bdp = cadd(b,d), bdm = csub(b,d);
    float2 jb  = jmulp(bdm);
    a = cadd(acp, bdp);
    c = csub(acp, bdp);
    if (INV) { b = cadd(acm, jb); d = csub(acm, jb); }
    else     { b = csub(acm, jb); d = cadd(acm, jb); }
}

#define C16_1 0.9238795325112867f
#define S16_1 0.3826834323650898f
#define R16_2 0.7071067811865476f

template<int INV>
__device__ __forceinline__ void dft16(float2 v[16]) {
    const float sg = INV ? 1.f : -1.f;
    bf4<INV>(v[0], v[4], v[8],  v[12]);
    bf4<INV>(v[1], v[5], v[9],  v[13]);
    bf4<INV>(v[2], v[6], v[10], v[14]);
    bf4<INV>(v[3], v[7], v[11], v[15]);
    const float2 w1 = make_float2( C16_1, sg*S16_1);
    const float2 w2 = make_float2( R16_2, sg*R16_2);
    const float2 w3 = make_float2( S16_1, sg*C16_1);
    const float2 w6 = make_float2(-R16_2, sg*R16_2);
    const float2 w9 = make_float2(-C16_1,-sg*S16_1);
    v[5]  = cmul(v[5],  w1);
    v[6]  = cmul(v[6],  w2);
    v[7]  = cmul(v[7],  w3);
    v[9]  = cmul(v[9],  w2);
    v[10] = INV ? jmulp(v[10]) : make_float2(v[10].y, -v[10].x);
    v[11] = cmul(v[11], w6);
    v[13] = cmul(v[13], w3);
    v[14] = cmul(v[14], w6);
    v[15] = cmul(v[15], w9);
    bf4<INV>(v[0],  v[1],  v[2],  v[3]);
    bf4<INV>(v[4],  v[5],  v[6],  v[7]);
    bf4<INV>(v[8],  v[9],  v[10], v[11]);
    bf4<INV>(v[12], v[13], v[14], v[15]);
}

__host__ __device__ constexpr int oidx(int r) { return ((r & 3) << 2) | (r >> 2); }
__device__ __forceinline__ int phz(int t) { return t ^ (((t >> 4) ^ (t >> 8)) & 15); }

__global__ __launch_bounds__(256) void fft16_filter(const ushort* __restrict__ VT,
                                                    ushort* __restrict__ yT,
                                                    const float2* __restrict__ tw,
                                                    const float2* __restrict__ Cdr) {
    __shared__ float2 X[4096];
    const int tid = threadIdx.x;
    const int b   = blockIdx.x >> 9;
    const int dp  = blockIdx.x & 511;
    const int d0  = dp << 1;
    const int h   = dp >> 5;

    const ushort* srcRe = VT + (size_t)d0 * M_ROWS + b * T_LEN;
    const ushort* srcIm = VT + (size_t)(d0 + 1) * M_ROWS + b * T_LEN;

    float2 v[16];
#pragma unroll
    for (int j = 0; j < 16; j++)
        v[j] = make_float2(bf2f(srcRe[tid + (j << 8)]), bf2f(srcIm[tid + (j << 8)]));

    dft16<0>(v);
#pragma unroll
    for (int r = 1; r < 16; r++) v[oidx(r)] = cmul(v[oidx(r)], tw[tid * r]);
#pragma unroll
    for (int r = 0; r < 16; r++) X[phz(tid + (r << 8))] = v[oidx(r)];
    __syncthreads();

    const int p2 = tid & 15, g2 = tid >> 4;
    const int base2 = (g2 << 8) + p2;
#pragma unroll
    for (int j = 0; j < 16; j++) v[j] = X[phz(base2 + (j << 4))];
    dft16<0>(v);
#pragma unroll
    for (int r = 1; r < 16; r++) v[oidx(r)] = cmul(v[oidx(r)], tw[(p2 * r) << 4]);
    __syncthreads();
#pragma unroll
    for (int r = 0; r < 16; r++) X[phz(base2 + (r << 4))] = v[oidx(r)];
    __syncthreads();

    const int base3 = tid << 4;
#pragma unroll
    for (int j = 0; j < 16; j++) v[j] = X[phz(base3 + j)];
    dft16<0>(v);
    const float2* Ch = Cdr + (h << 12) + base3;
#pragma unroll
    for (int r = 0; r < 16; r++) v[oidx(r)] = cmul(v[oidx(r)], Ch[r]);
    float2 u[16];
#pragma unroll
    for (int j = 0; j < 16; j++) u[j] = v[oidx(j)];
    dft16<1>(u);
    __syncthreads();
#pragma unroll
    for (int r = 0; r < 16; r++) X[phz(base3 + r)] = u[oidx(r)];
    __syncthreads();

#pragma unroll
    for (int j = 0; j < 16; j++) v[j] = X[phz(base2 + (j << 4))];
#pragma unroll
    for (int j = 1; j < 16; j++) v[j] = cmulc(v[j], tw[(p2 * j) << 4]);
    dft16<1>(v);
    __syncthreads();
#pragma unroll
    for (int r = 0; r < 16; r++) X[phz(base2 + (r << 4))] = v[oidx(r)];
    __syncthreads();

#pragma unroll
    for (int j = 0; j < 16; j++) v[j] = X[phz(tid + (j << 8))];
#pragma unroll
    for (int j = 1; j < 16; j++) v[j] = cmulc(v[j], tw[tid * j]);
    dft16<1>(v);
    ushort* dstRe = yT + (size_t)d0 * M_ROWS + b * T_LEN;
    ushort* dstIm = yT + (size_t)(d0 + 1) * M_ROWS + b * T_LEN;
    const float sc = 1.0f / 4096.0f;
#pragma unroll
    for (int r = 0; r < 16; r++) {
        float2 val = v[oidx(r)];
        dstRe[tid + (r << 8)] = f2bf(val.x * sc);
        dstIm[tid + (r << 8)] = f2bf(val.y * sc);
    }
}

// ---------------------------------------------------------------- transpose
__global__ __launch_bounds__(256) void transpose_yT(const ushort* __restrict__ src,
                                                    ushort* __restrict__ dst) {
    __shared__ ushort tile[4096];
    const int tid = threadIdx.x;
    const int bm = blockIdx.x & 255;
    const int bd = blockIdx.x >> 8;
    const int m0 = bm << 6, d0 = bd << 6;
#pragma unroll
    for (int i = 0; i < 2; i++) {
        int vn = tid + (i << 8);
        int r  = vn >> 3;
        int c8 = (vn & 7) << 3;
        u16x8 val = *(const u16x8*)&src[(size_t)(d0 + r) * M_ROWS + m0 + c8];
#pragma unroll
        for (int q = 0; q < 8; q++)
            tile[(r << 6) | ((c8 + q) ^ r)] = (ushort)val[q];
    }
    __syncthreads();
    const int dc = tid & 63;
    const int wb = tid >> 6;
#pragma unroll
    for (int i = 0; i < 16; i++) {
        int mr = wb + (i << 2);
        dst[(size_t)(m0 + mr) * D_DIM + d0 + dc] = tile[(dc << 6) | (mr ^ dc)];
    }
}

// ---------------------------------------------------------------- launch
extern "C" void kernel_launch(void* const* d_in, const int* in_sizes, int n_in,
                              void* d_out, int out_size, void* d_ws, size_t ws_size,
                              hipStream_t stream) {
    const float* x    = (const float*)d_in[0];
    const float* Wqkv = (const float*)d_in[1];
    const float* bqkv = (const float*)d_in[2];
    const float* Wo   = (const float*)d_in[3];
    const float* bo   = (const float*)d_in[4];
    const float* lg   = (const float*)d_in[5];
    const float* ph   = (const float*)d_in[6];

    char* ws = (char*)d_ws;
    ushort* xb  = (ushort*)ws;                      // 33,554,432 B: x bf16; later y natural
    ushort* Wvb = (ushort*)(ws + 33554432);         //  2,097,152 B
    ushort* Wob = (ushort*)(ws + 35651584);         //  2,097,152 B
    float2* tw  = (float2*)(ws + 37748736);         //     32,768 B
    float2* Cdr = (float2*)(ws + 37781504);         //    524,288 B

    ushort* VT   = (ushort*)d_out;                          // [1024][16384] lower half
    ushort* yT   = (ushort*)((char*)d_out + 33554432);      // [1024][16384] upper half
    ushort* ynat = xb;                                      // [16384][1024] after gemm1
    float*  out  = (float*)d_out;

    prep_tw<<<16, 256, 0, stream>>>(tw);
    prep_filter16<<<(H_HEADS * 4096) / 256, 256, 0, stream>>>(lg, ph, Cdr);
    cvt_f32_to_bf16<<<(16777216 / 4) / 256, 256, 0, stream>>>(x, xb, 16777216 / 4);
    cvt_f32_to_bf16<<<(1048576 / 4) / 256, 256, 0, stream>>>(Wqkv + 2048 * 1024, Wvb, 1048576 / 4);
    cvt_f32_to_bf16<<<(1048576 / 4) / 256, 256, 0, stream>>>(Wo, Wob, 1048576 / 4);

    // V^T[d][m] = sum_k Wv[d,k] x[m,k] + b_qkv[2D+d]
    gemm256<false, true><<<(D_DIM / 256) * (M_ROWS / 256), 512, 0, stream>>>(
        Wvb, xb, bqkv + 2 * D_DIM, nullptr, (void*)VT, D_DIM, M_ROWS, D_DIM);

    // spectral filter along T, coalesced rows: V^T -> y^T
    fft16_filter<<<B_BATCH * (D_DIM / 2), 256, 0, stream>>>(VT, yT, tw, Cdr);

    // y^T -> y natural layout (into xb, free after gemm1)
    transpose_yT<<<(M_ROWS / 64) * (D_DIM / 64), 256, 0, stream>>>(yT, ynat);

    // out = x + y @ Wo^T + b_o
    gemm256<true, false><<<(M_ROWS / 256) * (D_DIM / 256), 512, 0, stream>>>(
        ynat, Wob, bo, x, (void*)out, M_ROWS, D_DIM, D_DIM);
}